// Round 1
// baseline (1615.069 us; speedup 1.0000x reference)
//
#include <hip/hip_runtime.h>
#include <hip/hip_bf16.h>

#define LOG2F_ 0.69314718055994530942f

// softplus(x) - log(2), numerically stable
__device__ __forceinline__ float ssp(float x) {
    float e = __expf(-fabsf(x));
    return __logf(1.0f + e) + fmaxf(x, 0.0f) - LOG2F_;
}

// Edge filter network: h1 = ssp(bf@W1+b1); w = ssp(h1@W2+b2); m = w*eh;
// scatter-add m into sums[dst], count into cnt[dst].
__global__ __launch_bounds__(256) void edge_kernel(
    const float* __restrict__ bf, const float* __restrict__ eh,
    const float* __restrict__ W1, const float* __restrict__ b1,
    const float* __restrict__ W2, const float* __restrict__ b2,
    const int* __restrict__ dst,
    float* __restrict__ sums, float* __restrict__ cnt, int E)
{
    __shared__ float sW1[64][64];   // 16 KB
    __shared__ float sW2[64][64];   // 16 KB
    __shared__ float sb1[64], sb2[64];
    __shared__ float sX[64][65];    // [edge][feat], pad-1 -> conflict-free

    const int tid = threadIdx.x;
    for (int i = tid; i < 4096; i += 256) {
        sW1[i >> 6][i & 63] = W1[i];
        sW2[i >> 6][i & 63] = W2[i];
    }
    if (tid < 64) { sb1[tid] = b1[tid]; sb2[tid] = b2[tid]; }

    const int f4 = (tid & 15) << 2;   // feature base: 0,4,...,60
    const int e4 = (tid >> 4) << 2;   // edge base within tile: 0,4,...,60
    const int ntiles = (E + 63) >> 6;

    for (int t = blockIdx.x; t < ntiles; t += gridDim.x) {
        const int base = t << 6;
        __syncthreads();   // prior iter's sX reads done before restage
        // stage 64x64 bf tile, coalesced
        #pragma unroll
        for (int k = 0; k < 16; ++k) {
            int idx = (k << 8) + tid;
            int e = idx >> 6, r = idx & 63;
            int ge = base + e;
            sX[e][r] = (ge < E) ? bf[(size_t)ge * 64 + r] : 0.0f;
        }
        __syncthreads();

        // matmul 1: acc[i][j] = sum_r bf[e4+i][r] * W1[r][f4+j]
        float acc[4][4] = {{0.f,0.f,0.f,0.f},{0.f,0.f,0.f,0.f},
                           {0.f,0.f,0.f,0.f},{0.f,0.f,0.f,0.f}};
        #pragma unroll 8
        for (int r = 0; r < 64; ++r) {
            float xv[4];
            #pragma unroll
            for (int i = 0; i < 4; ++i) xv[i] = sX[e4 + i][r];
            float4 w4 = *(const float4*)&sW1[r][f4];
            #pragma unroll
            for (int i = 0; i < 4; ++i) {
                acc[i][0] = fmaf(xv[i], w4.x, acc[i][0]);
                acc[i][1] = fmaf(xv[i], w4.y, acc[i][1]);
                acc[i][2] = fmaf(xv[i], w4.z, acc[i][2]);
                acc[i][3] = fmaf(xv[i], w4.w, acc[i][3]);
            }
        }
        __syncthreads();
        // activation, h1 back into sX
        #pragma unroll
        for (int i = 0; i < 4; ++i)
            #pragma unroll
            for (int j = 0; j < 4; ++j)
                sX[e4 + i][f4 + j] = ssp(acc[i][j] + sb1[f4 + j]);
        __syncthreads();

        // matmul 2
        float acc2[4][4] = {{0.f,0.f,0.f,0.f},{0.f,0.f,0.f,0.f},
                            {0.f,0.f,0.f,0.f},{0.f,0.f,0.f,0.f}};
        #pragma unroll 8
        for (int r = 0; r < 64; ++r) {
            float xv[4];
            #pragma unroll
            for (int i = 0; i < 4; ++i) xv[i] = sX[e4 + i][r];
            float4 w4 = *(const float4*)&sW2[r][f4];
            #pragma unroll
            for (int i = 0; i < 4; ++i) {
                acc2[i][0] = fmaf(xv[i], w4.x, acc2[i][0]);
                acc2[i][1] = fmaf(xv[i], w4.y, acc2[i][1]);
                acc2[i][2] = fmaf(xv[i], w4.z, acc2[i][2]);
                acc2[i][3] = fmaf(xv[i], w4.w, acc2[i][3]);
            }
        }

        // epilogue: gate by eh, scatter-add
        #pragma unroll
        for (int i = 0; i < 4; ++i) {
            int ge = base + e4 + i;
            if (ge < E) {
                int d = dst[ge];
                float* srow = sums + (size_t)d * 64;
                float4 ev = *(const float4*)&eh[(size_t)ge * 64 + f4];
                float m0 = ssp(acc2[i][0] + sb2[f4 + 0]) * ev.x;
                float m1 = ssp(acc2[i][1] + sb2[f4 + 1]) * ev.y;
                float m2 = ssp(acc2[i][2] + sb2[f4 + 2]) * ev.z;
                float m3 = ssp(acc2[i][3] + sb2[f4 + 3]) * ev.w;
                atomicAdd(&srow[f4 + 0], m0);
                atomicAdd(&srow[f4 + 1], m1);
                atomicAdd(&srow[f4 + 2], m2);
                atomicAdd(&srow[f4 + 3], m3);
                if (f4 == 0) atomicAdd(&cnt[d], 1.0f);
            }
        }
    }
}

// Node interaction block: h = sums/max(cnt,1); out = ssp(h@W3+b3)
__global__ __launch_bounds__(256) void node_kernel(
    const float* __restrict__ sums, const float* __restrict__ cnt,
    const float* __restrict__ W3, const float* __restrict__ b3,
    float* __restrict__ out, int N)
{
    __shared__ float sW[64][64];
    __shared__ float sb[64];
    __shared__ float sC[64];
    __shared__ float sX[64][65];

    const int tid = threadIdx.x;
    for (int i = tid; i < 4096; i += 256) sW[i >> 6][i & 63] = W3[i];
    if (tid < 64) sb[tid] = b3[tid];

    const int f4 = (tid & 15) << 2;
    const int e4 = (tid >> 4) << 2;
    const int ntiles = (N + 63) >> 6;

    for (int t = blockIdx.x; t < ntiles; t += gridDim.x) {
        const int base = t << 6;
        __syncthreads();
        if (tid < 64) {
            int gn = base + tid;
            sC[tid] = (gn < N) ? 1.0f / fmaxf(cnt[gn], 1.0f) : 0.0f;
        }
        __syncthreads();
        #pragma unroll
        for (int k = 0; k < 16; ++k) {
            int idx = (k << 8) + tid;
            int n = idx >> 6, r = idx & 63;
            int gn = base + n;
            sX[n][r] = (gn < N) ? sums[(size_t)gn * 64 + r] * sC[n] : 0.0f;
        }
        __syncthreads();

        float acc[4][4] = {{0.f,0.f,0.f,0.f},{0.f,0.f,0.f,0.f},
                           {0.f,0.f,0.f,0.f},{0.f,0.f,0.f,0.f}};
        #pragma unroll 8
        for (int r = 0; r < 64; ++r) {
            float xv[4];
            #pragma unroll
            for (int i = 0; i < 4; ++i) xv[i] = sX[e4 + i][r];
            float4 w4 = *(const float4*)&sW[r][f4];
            #pragma unroll
            for (int i = 0; i < 4; ++i) {
                acc[i][0] = fmaf(xv[i], w4.x, acc[i][0]);
                acc[i][1] = fmaf(xv[i], w4.y, acc[i][1]);
                acc[i][2] = fmaf(xv[i], w4.z, acc[i][2]);
                acc[i][3] = fmaf(xv[i], w4.w, acc[i][3]);
            }
        }

        #pragma unroll
        for (int i = 0; i < 4; ++i) {
            int gn = base + e4 + i;
            if (gn < N) {
                float4 o;
                o.x = ssp(acc[i][0] + sb[f4 + 0]);
                o.y = ssp(acc[i][1] + sb[f4 + 1]);
                o.z = ssp(acc[i][2] + sb[f4 + 2]);
                o.w = ssp(acc[i][3] + sb[f4 + 3]);
                *(float4*)&out[(size_t)gn * 64 + f4] = o;
            }
        }
    }
}

extern "C" void kernel_launch(void* const* d_in, const int* in_sizes, int n_in,
                              void* d_out, int out_size, void* d_ws, size_t ws_size,
                              hipStream_t stream) {
    const float* bf = (const float*)d_in[0];
    const float* eh = (const float*)d_in[1];
    const float* W1 = (const float*)d_in[2];
    const float* b1 = (const float*)d_in[3];
    const float* W2 = (const float*)d_in[4];
    const float* b2 = (const float*)d_in[5];
    const float* W3 = (const float*)d_in[6];
    const float* b3 = (const float*)d_in[7];
    const int*   dst = (const int*)d_in[8];

    const int E = in_sizes[0] / 64;
    const int N = out_size / 64;        // out is [N, 64]

    float* sums = (float*)d_ws;
    float* cnt  = sums + (size_t)N * 64;

    hipMemsetAsync(d_ws, 0, ((size_t)N * 64 + N) * sizeof(float), stream);

    const int ntiles = (E + 63) >> 6;
    const int grid = ntiles < 3125 ? ntiles : 3125;
    edge_kernel<<<grid, 256, 0, stream>>>(bf, eh, W1, b1, W2, b2, dst, sums, cnt, E);

    const int ntilesN = (N + 63) >> 6;
    node_kernel<<<ntilesN, 256, 0, stream>>>(sums, cnt, W3, b3, (float*)d_out, N);
}

// Round 2
// 784.225 us; speedup vs baseline: 2.0594x; 2.0594x over previous
//
#include <hip/hip_runtime.h>
#include <hip/hip_bf16.h>

#define LOG2F_ 0.69314718055994530942f

// softplus(x) - log(2), numerically stable
__device__ __forceinline__ float ssp(float x) {
    float e = __expf(-fabsf(x));
    return __logf(1.0f + e) + fmaxf(x, 0.0f) - LOG2F_;
}

// Edge filter network: h1 = ssp(bf@W1+b1); w = ssp(h1@W2+b2); m = w*eh;
// scatter-add m into sums[dst] (coalesced full-row atomics), count into cnt[dst].
__global__ __launch_bounds__(256) void edge_kernel(
    const float* __restrict__ bf, const float* __restrict__ eh,
    const float* __restrict__ W1, const float* __restrict__ b1,
    const float* __restrict__ W2, const float* __restrict__ b2,
    const int* __restrict__ dst,
    float* __restrict__ sums, float* __restrict__ cnt, int E)
{
    __shared__ float sW1[64][64];   // 16 KB
    __shared__ float sW2[64][64];   // 16 KB
    __shared__ float sb1[64], sb2[64];
    __shared__ float sX[64][65];    // [edge][feat], pad-1 -> conflict-free
    __shared__ int   sD[64];        // dst per edge in tile

    const int tid = threadIdx.x;
    for (int i = tid; i < 4096; i += 256) {
        sW1[i >> 6][i & 63] = W1[i];
        sW2[i >> 6][i & 63] = W2[i];
    }
    if (tid < 64) { sb1[tid] = b1[tid]; sb2[tid] = b2[tid]; }

    const int f4 = (tid & 15) << 2;   // feature base: 0,4,...,60
    const int e4 = (tid >> 4) << 2;   // edge base within tile: 0,4,...,60
    const int lane = tid & 63;
    const int wv   = tid >> 6;        // wave id 0..3
    const int ntiles = (E + 63) >> 6;

    for (int t = blockIdx.x; t < ntiles; t += gridDim.x) {
        const int base = t << 6;
        __syncthreads();   // prior iter's sX reads (atomic phase) done before restage
        // stage 64x64 bf tile + dst, coalesced
        #pragma unroll
        for (int k = 0; k < 16; ++k) {
            int idx = (k << 8) + tid;
            int e = idx >> 6, r = idx & 63;
            int ge = base + e;
            sX[e][r] = (ge < E) ? bf[(size_t)ge * 64 + r] : 0.0f;
        }
        if (tid < 64) sD[tid] = (base + tid < E) ? dst[base + tid] : 0;
        __syncthreads();

        // matmul 1: acc[i][j] = sum_r bf[e4+i][r] * W1[r][f4+j]
        float acc[4][4] = {{0.f,0.f,0.f,0.f},{0.f,0.f,0.f,0.f},
                           {0.f,0.f,0.f,0.f},{0.f,0.f,0.f,0.f}};
        #pragma unroll 8
        for (int r = 0; r < 64; ++r) {
            float xv[4];
            #pragma unroll
            for (int i = 0; i < 4; ++i) xv[i] = sX[e4 + i][r];
            float4 w4 = *(const float4*)&sW1[r][f4];
            #pragma unroll
            for (int i = 0; i < 4; ++i) {
                acc[i][0] = fmaf(xv[i], w4.x, acc[i][0]);
                acc[i][1] = fmaf(xv[i], w4.y, acc[i][1]);
                acc[i][2] = fmaf(xv[i], w4.z, acc[i][2]);
                acc[i][3] = fmaf(xv[i], w4.w, acc[i][3]);
            }
        }
        __syncthreads();
        // activation, h1 back into sX
        #pragma unroll
        for (int i = 0; i < 4; ++i)
            #pragma unroll
            for (int j = 0; j < 4; ++j)
                sX[e4 + i][f4 + j] = ssp(acc[i][j] + sb1[f4 + j]);
        __syncthreads();

        // matmul 2
        float acc2[4][4] = {{0.f,0.f,0.f,0.f},{0.f,0.f,0.f,0.f},
                            {0.f,0.f,0.f,0.f},{0.f,0.f,0.f,0.f}};
        #pragma unroll 8
        for (int r = 0; r < 64; ++r) {
            float xv[4];
            #pragma unroll
            for (int i = 0; i < 4; ++i) xv[i] = sX[e4 + i][r];
            float4 w4 = *(const float4*)&sW2[r][f4];
            #pragma unroll
            for (int i = 0; i < 4; ++i) {
                acc2[i][0] = fmaf(xv[i], w4.x, acc2[i][0]);
                acc2[i][1] = fmaf(xv[i], w4.y, acc2[i][1]);
                acc2[i][2] = fmaf(xv[i], w4.z, acc2[i][2]);
                acc2[i][3] = fmaf(xv[i], w4.w, acc2[i][3]);
            }
        }
        __syncthreads();   // matmul-2 reads of sX done before m overwrites it

        // epilogue part 1: gate by eh, deposit m into sX
        #pragma unroll
        for (int i = 0; i < 4; ++i) {
            int ge = base + e4 + i;
            if (ge < E) {
                float4 ev = *(const float4*)&eh[(size_t)ge * 64 + f4];
                sX[e4 + i][f4 + 0] = ssp(acc2[i][0] + sb2[f4 + 0]) * ev.x;
                sX[e4 + i][f4 + 1] = ssp(acc2[i][1] + sb2[f4 + 1]) * ev.y;
                sX[e4 + i][f4 + 2] = ssp(acc2[i][2] + sb2[f4 + 2]) * ev.z;
                sX[e4 + i][f4 + 3] = ssp(acc2[i][3] + sb2[f4 + 3]) * ev.w;
            }
        }
        __syncthreads();

        // epilogue part 2: coalesced row atomics — wave wv owns edges 16wv..16wv+15;
        // one atomic instruction covers a full 256B destination row (4 cachelines).
        #pragma unroll
        for (int i = 0; i < 16; ++i) {
            int e = (wv << 4) + i;
            int ge = base + e;               // wave-uniform, no divergence
            if (ge < E) {
                int d = sD[e];
                atomicAdd(&sums[(size_t)d * 64 + lane], sX[e][lane]);
                if (lane == 0) atomicAdd(&cnt[d], 1.0f);
            }
        }
    }
}

// Node interaction block: h = sums/max(cnt,1); out = ssp(h@W3+b3)
__global__ __launch_bounds__(256) void node_kernel(
    const float* __restrict__ sums, const float* __restrict__ cnt,
    const float* __restrict__ W3, const float* __restrict__ b3,
    float* __restrict__ out, int N)
{
    __shared__ float sW[64][64];
    __shared__ float sb[64];
    __shared__ float sC[64];
    __shared__ float sX[64][65];

    const int tid = threadIdx.x;
    for (int i = tid; i < 4096; i += 256) sW[i >> 6][i & 63] = W3[i];
    if (tid < 64) sb[tid] = b3[tid];

    const int f4 = (tid & 15) << 2;
    const int e4 = (tid >> 4) << 2;
    const int ntiles = (N + 63) >> 6;

    for (int t = blockIdx.x; t < ntiles; t += gridDim.x) {
        const int base = t << 6;
        __syncthreads();
        if (tid < 64) {
            int gn = base + tid;
            sC[tid] = (gn < N) ? 1.0f / fmaxf(cnt[gn], 1.0f) : 0.0f;
        }
        __syncthreads();
        #pragma unroll
        for (int k = 0; k < 16; ++k) {
            int idx = (k << 8) + tid;
            int n = idx >> 6, r = idx & 63;
            int gn = base + n;
            sX[n][r] = (gn < N) ? sums[(size_t)gn * 64 + r] * sC[n] : 0.0f;
        }
        __syncthreads();

        float acc[4][4] = {{0.f,0.f,0.f,0.f},{0.f,0.f,0.f,0.f},
                           {0.f,0.f,0.f,0.f},{0.f,0.f,0.f,0.f}};
        #pragma unroll 8
        for (int r = 0; r < 64; ++r) {
            float xv[4];
            #pragma unroll
            for (int i = 0; i < 4; ++i) xv[i] = sX[e4 + i][r];
            float4 w4 = *(const float4*)&sW[r][f4];
            #pragma unroll
            for (int i = 0; i < 4; ++i) {
                acc[i][0] = fmaf(xv[i], w4.x, acc[i][0]);
                acc[i][1] = fmaf(xv[i], w4.y, acc[i][1]);
                acc[i][2] = fmaf(xv[i], w4.z, acc[i][2]);
                acc[i][3] = fmaf(xv[i], w4.w, acc[i][3]);
            }
        }

        #pragma unroll
        for (int i = 0; i < 4; ++i) {
            int gn = base + e4 + i;
            if (gn < N) {
                float4 o;
                o.x = ssp(acc[i][0] + sb[f4 + 0]);
                o.y = ssp(acc[i][1] + sb[f4 + 1]);
                o.z = ssp(acc[i][2] + sb[f4 + 2]);
                o.w = ssp(acc[i][3] + sb[f4 + 3]);
                *(float4*)&out[(size_t)gn * 64 + f4] = o;
            }
        }
    }
}

extern "C" void kernel_launch(void* const* d_in, const int* in_sizes, int n_in,
                              void* d_out, int out_size, void* d_ws, size_t ws_size,
                              hipStream_t stream) {
    const float* bf = (const float*)d_in[0];
    const float* eh = (const float*)d_in[1];
    const float* W1 = (const float*)d_in[2];
    const float* b1 = (const float*)d_in[3];
    const float* W2 = (const float*)d_in[4];
    const float* b2 = (const float*)d_in[5];
    const float* W3 = (const float*)d_in[6];
    const float* b3 = (const float*)d_in[7];
    const int*   dst = (const int*)d_in[8];

    const int E = in_sizes[0] / 64;
    const int N = out_size / 64;        // out is [N, 64]

    float* sums = (float*)d_ws;
    float* cnt  = sums + (size_t)N * 64;

    hipMemsetAsync(d_ws, 0, ((size_t)N * 64 + N) * sizeof(float), stream);

    const int ntiles = (E + 63) >> 6;
    const int grid = ntiles < 3125 ? ntiles : 3125;
    edge_kernel<<<grid, 256, 0, stream>>>(bf, eh, W1, b1, W2, b2, dst, sums, cnt, E);

    const int ntilesN = (N + 63) >> 6;
    node_kernel<<<ntilesN, 256, 0, stream>>>(sums, cnt, W3, b3, (float*)d_out, N);
}

// Round 3
// 591.089 us; speedup vs baseline: 2.7324x; 1.3267x over previous
//
#include <hip/hip_runtime.h>
#include <hip/hip_bf16.h>

#define LOG2F_ 0.69314718055994530942f

typedef __attribute__((ext_vector_type(8))) short s8bf;   // 8 bf16 (4 VGPRs)
typedef __attribute__((ext_vector_type(4))) float f32x4;  // MFMA C/D

// softplus(x) - log(2), numerically stable
__device__ __forceinline__ float ssp(float x) {
    float e = __expf(-fabsf(x));
    return __logf(1.0f + e) + fmaxf(x, 0.0f) - LOG2F_;
}

__device__ __forceinline__ short bf_hi(float x) {
    __hip_bfloat16 h = __float2bfloat16(x);
    return *reinterpret_cast<short*>(&h);
}
__device__ __forceinline__ float bf_to_f(short s) {
    __hip_bfloat16 h;
    *reinterpret_cast<short*>(&h) = s;
    return __bfloat162float(h);
}

// Edge filter network with bf16x2-split MFMA matmuls.
// Per-wave 16-edge tiles, barrier-free main loop, W1/W2 fragments in registers.
__global__ __launch_bounds__(256, 2) void edge_kernel(
    const float* __restrict__ bf, const float* __restrict__ eh,
    const float* __restrict__ W1, const float* __restrict__ b1,
    const float* __restrict__ W2, const float* __restrict__ b2,
    const int* __restrict__ dst,
    float* __restrict__ sums, float* __restrict__ cnt, int E)
{
    // per-wave region: X bf16 hi (2KB) + lo (2KB) [overlaid by h1 f32 4KB] + ehm f32 16x68 (4352B)
    __shared__ __align__(16) unsigned char lds[4 * 8448];

    const int tid  = threadIdx.x;
    const int lane = tid & 63;
    const int wv   = tid >> 6;
    const int g    = lane >> 4;     // 16-lane group 0..3
    const int n16  = lane & 15;

    // ---- init: build W1/W2 bf16-split B-fragments in registers ----
    // B-frag (nt, k0i): lane holds W[k0i*32 + g*8 + j][nt*16 + n16], j=0..7
    s8bf w1h[4][2], w1l[4][2], w2h[4][2], w2l[4][2];
    {
        float* wst = (float*)lds;   // 16KB staging (pre-loop only)
        for (int i = tid; i < 4096; i += 256) wst[i] = W1[i];
        __syncthreads();
        #pragma unroll
        for (int nt = 0; nt < 4; ++nt)
            #pragma unroll
            for (int k0i = 0; k0i < 2; ++k0i)
                #pragma unroll
                for (int j = 0; j < 8; ++j) {
                    float v = wst[(k0i * 32 + g * 8 + j) * 64 + nt * 16 + n16];
                    short h = bf_hi(v);
                    w1h[nt][k0i][j] = h;
                    w1l[nt][k0i][j] = bf_hi(v - bf_to_f(h));
                }
        __syncthreads();
        for (int i = tid; i < 4096; i += 256) wst[i] = W2[i];
        __syncthreads();
        #pragma unroll
        for (int nt = 0; nt < 4; ++nt)
            #pragma unroll
            for (int k0i = 0; k0i < 2; ++k0i)
                #pragma unroll
                for (int j = 0; j < 8; ++j) {
                    float v = wst[(k0i * 32 + g * 8 + j) * 64 + nt * 16 + n16];
                    short h = bf_hi(v);
                    w2h[nt][k0i][j] = h;
                    w2l[nt][k0i][j] = bf_hi(v - bf_to_f(h));
                }
        __syncthreads();   // last barrier — main loop is barrier-free
    }

    // bias fragments: C/D col = n16 + 16*nt
    float b1v[4], b2v[4];
    #pragma unroll
    for (int nt = 0; nt < 4; ++nt) {
        b1v[nt] = b1[nt * 16 + n16];
        b2v[nt] = b2[nt * 16 + n16];
    }

    unsigned char* wbase = lds + wv * 8448;
    char* Xh = (char*)wbase;              // [16][64] bf16, swizzled
    char* Xl = (char*)wbase + 2048;
    float* ehm = (float*)(wbase + 4096);  // [16][68] f32 (pad 68 -> 2-way max)

    const int r4  = lane >> 2;            // staging row 0..15
    const int c16 = (lane & 3) << 4;      // staging col base
    const int s0  = (lane & 3) << 1;      // 16B slot base in bf16 row
    const int crow = g << 2;              // C-frag row base

    const int wave_id = (blockIdx.x << 2) + wv;
    const int nwaves  = gridDim.x << 2;
    const int ntiles  = (E + 15) >> 4;

    for (int t = wave_id; t < ntiles; t += nwaves) {
        const int base = t << 4;

        // ---- stage: bf -> Xh/Xl (bf16 split, swizzled), eh -> ehm (f32) ----
        float xs[16], es[16];
        {
            const size_t roff = (size_t)(base + r4) * 64 + c16;
            if (base + r4 < E) {
                *(float4*)&xs[0]  = *(const float4*)(bf + roff);
                *(float4*)&xs[4]  = *(const float4*)(bf + roff + 4);
                *(float4*)&xs[8]  = *(const float4*)(bf + roff + 8);
                *(float4*)&xs[12] = *(const float4*)(bf + roff + 12);
                *(float4*)&es[0]  = *(const float4*)(eh + roff);
                *(float4*)&es[4]  = *(const float4*)(eh + roff + 4);
                *(float4*)&es[8]  = *(const float4*)(eh + roff + 8);
                *(float4*)&es[12] = *(const float4*)(eh + roff + 12);
            } else {
                #pragma unroll
                for (int j = 0; j < 16; ++j) { xs[j] = 0.0f; es[j] = 0.0f; }
            }
        }
        s8bf hv0, hv1, lv0, lv1;
        #pragma unroll
        for (int j = 0; j < 8; ++j) {
            short h = bf_hi(xs[j]);     hv0[j] = h; lv0[j] = bf_hi(xs[j] - bf_to_f(h));
            short h2 = bf_hi(xs[8 + j]); hv1[j] = h2; lv1[j] = bf_hi(xs[8 + j] - bf_to_f(h2));
        }
        {
            const int sw = (r4 & 7) << 4;
            const int a0 = r4 * 128 + (((s0) << 4) ^ sw);
            const int a1 = r4 * 128 + (((s0 + 1) << 4) ^ sw);
            *(s8bf*)(Xh + a0) = hv0;  *(s8bf*)(Xh + a1) = hv1;
            *(s8bf*)(Xl + a0) = lv0;  *(s8bf*)(Xl + a1) = lv1;
            float* ew = ehm + r4 * 68 + c16;
            *(float4*)(ew)      = *(float4*)&es[0];
            *(float4*)(ew + 4)  = *(float4*)&es[4];
            *(float4*)(ew + 8)  = *(float4*)&es[8];
            *(float4*)(ew + 12) = *(float4*)&es[12];
        }

        // ---- matmul 1: acc0 = X @ W1 (split: hh + hl + lh) ----
        f32x4 acc0[4];
        #pragma unroll
        for (int nt = 0; nt < 4; ++nt) acc0[nt] = (f32x4){0.f, 0.f, 0.f, 0.f};
        #pragma unroll
        for (int k0i = 0; k0i < 2; ++k0i) {
            const int sA = (k0i << 2) + g;           // 16B slot: k0/8 + g
            const int ab = n16 * 128 + ((sA << 4) ^ ((n16 & 7) << 4));
            s8bf ah = *(s8bf*)(Xh + ab);
            s8bf al = *(s8bf*)(Xl + ab);
            #pragma unroll
            for (int nt = 0; nt < 4; ++nt) {
                acc0[nt] = __builtin_amdgcn_mfma_f32_16x16x32_bf16(ah, w1h[nt][k0i], acc0[nt], 0, 0, 0);
                acc0[nt] = __builtin_amdgcn_mfma_f32_16x16x32_bf16(ah, w1l[nt][k0i], acc0[nt], 0, 0, 0);
                acc0[nt] = __builtin_amdgcn_mfma_f32_16x16x32_bf16(al, w1h[nt][k0i], acc0[nt], 0, 0, 0);
            }
        }

        // ---- h1 = ssp(acc0 + b1) -> f32 LDS (overlays Xh/Xl), swizzled ----
        #pragma unroll
        for (int nt = 0; nt < 4; ++nt)
            #pragma unroll
            for (int r = 0; r < 4; ++r) {
                float h = ssp(acc0[nt][r] + b1v[nt]);
                int row = crow + r;
                int bcol = (nt * 16 + n16) << 2;
                *(float*)((char*)wbase + row * 256 + (bcol ^ ((row & 7) << 4))) = h;
            }

        // ---- matmul 2: acc2 = h1 @ W2 (A-frags rebuilt from f32, split) ----
        f32x4 acc2[4];
        #pragma unroll
        for (int nt = 0; nt < 4; ++nt) acc2[nt] = (f32x4){0.f, 0.f, 0.f, 0.f};
        #pragma unroll
        for (int k0i = 0; k0i < 2; ++k0i) {
            const int bc = k0i * 128 + g * 32;       // byte col of 8 floats
            const int sw = (n16 & 7) << 4;
            const int rb = n16 * 256;
            f32x4 f0 = *(f32x4*)((char*)wbase + rb + ((bc) ^ sw));
            f32x4 f1 = *(f32x4*)((char*)wbase + rb + ((bc + 16) ^ sw));
            s8bf ah, al;
            #pragma unroll
            for (int j = 0; j < 4; ++j) {
                short h = bf_hi(f0[j]);  ah[j] = h;     al[j] = bf_hi(f0[j] - bf_to_f(h));
                short h2 = bf_hi(f1[j]); ah[4 + j] = h2; al[4 + j] = bf_hi(f1[j] - bf_to_f(h2));
            }
            #pragma unroll
            for (int nt = 0; nt < 4; ++nt) {
                acc2[nt] = __builtin_amdgcn_mfma_f32_16x16x32_bf16(ah, w2h[nt][k0i], acc2[nt], 0, 0, 0);
                acc2[nt] = __builtin_amdgcn_mfma_f32_16x16x32_bf16(ah, w2l[nt][k0i], acc2[nt], 0, 0, 0);
                acc2[nt] = __builtin_amdgcn_mfma_f32_16x16x32_bf16(al, w2h[nt][k0i], acc2[nt], 0, 0, 0);
            }
        }

        // ---- epilogue: m = ssp(acc2 + b2) * eh, in-place in ehm ----
        #pragma unroll
        for (int nt = 0; nt < 4; ++nt)
            #pragma unroll
            for (int r = 0; r < 4; ++r) {
                float w = ssp(acc2[nt][r] + b2v[nt]);
                int row = crow + r;
                float* p = ehm + row * 68 + nt * 16 + n16;
                *p = w * (*p);
            }

        // ---- scatter: one full 256B row-atomic per edge ----
        #pragma unroll 4
        for (int e = 0; e < 16; ++e) {
            int gedge = base + e;
            if (gedge < E) {
                int d = dst[gedge];                  // uniform -> s_load
                atomicAdd(&sums[(size_t)d * 64 + lane], ehm[e * 68 + lane]);
            }
        }
        if (lane < 16 && base + lane < E) atomicAdd(&cnt[dst[base + lane]], 1.0f);
    }
}

// Node interaction block: h = sums/max(cnt,1); out = ssp(h@W3+b3)
__global__ __launch_bounds__(256) void node_kernel(
    const float* __restrict__ sums, const float* __restrict__ cnt,
    const float* __restrict__ W3, const float* __restrict__ b3,
    float* __restrict__ out, int N)
{
    __shared__ float sW[64][64];
    __shared__ float sb[64];
    __shared__ float sC[64];
    __shared__ float sX[64][65];

    const int tid = threadIdx.x;
    for (int i = tid; i < 4096; i += 256) sW[i >> 6][i & 63] = W3[i];
    if (tid < 64) sb[tid] = b3[tid];

    const int f4 = (tid & 15) << 2;
    const int e4 = (tid >> 4) << 2;
    const int ntiles = (N + 63) >> 6;

    for (int t = blockIdx.x; t < ntiles; t += gridDim.x) {
        const int base = t << 6;
        __syncthreads();
        if (tid < 64) {
            int gn = base + tid;
            sC[tid] = (gn < N) ? 1.0f / fmaxf(cnt[gn], 1.0f) : 0.0f;
        }
        __syncthreads();
        #pragma unroll
        for (int k = 0; k < 16; ++k) {
            int idx = (k << 8) + tid;
            int n = idx >> 6, r = idx & 63;
            int gn = base + n;
            sX[n][r] = (gn < N) ? sums[(size_t)gn * 64 + r] * sC[n] : 0.0f;
        }
        __syncthreads();

        float acc[4][4] = {{0.f,0.f,0.f,0.f},{0.f,0.f,0.f,0.f},
                           {0.f,0.f,0.f,0.f},{0.f,0.f,0.f,0.f}};
        #pragma unroll 8
        for (int r = 0; r < 64; ++r) {
            float xv[4];
            #pragma unroll
            for (int i = 0; i < 4; ++i) xv[i] = sX[e4 + i][r];
            float4 w4 = *(const float4*)&sW[r][f4];
            #pragma unroll
            for (int i = 0; i < 4; ++i) {
                acc[i][0] = fmaf(xv[i], w4.x, acc[i][0]);
                acc[i][1] = fmaf(xv[i], w4.y, acc[i][1]);
                acc[i][2] = fmaf(xv[i], w4.z, acc[i][2]);
                acc[i][3] = fmaf(xv[i], w4.w, acc[i][3]);
            }
        }

        #pragma unroll
        for (int i = 0; i < 4; ++i) {
            int gn = base + e4 + i;
            if (gn < N) {
                float4 o;
                o.x = ssp(acc[i][0] + sb[f4 + 0]);
                o.y = ssp(acc[i][1] + sb[f4 + 1]);
                o.z = ssp(acc[i][2] + sb[f4 + 2]);
                o.w = ssp(acc[i][3] + sb[f4 + 3]);
                *(float4*)&out[(size_t)gn * 64 + f4] = o;
            }
        }
    }
}

extern "C" void kernel_launch(void* const* d_in, const int* in_sizes, int n_in,
                              void* d_out, int out_size, void* d_ws, size_t ws_size,
                              hipStream_t stream) {
    const float* bf = (const float*)d_in[0];
    const float* eh = (const float*)d_in[1];
    const float* W1 = (const float*)d_in[2];
    const float* b1 = (const float*)d_in[3];
    const float* W2 = (const float*)d_in[4];
    const float* b2 = (const float*)d_in[5];
    const float* W3 = (const float*)d_in[6];
    const float* b3 = (const float*)d_in[7];
    const int*   dst = (const int*)d_in[8];

    const int E = in_sizes[0] / 64;
    const int N = out_size / 64;        // out is [N, 64]

    float* sums = (float*)d_ws;
    float* cnt  = sums + (size_t)N * 64;

    hipMemsetAsync(d_ws, 0, ((size_t)N * 64 + N) * sizeof(float), stream);

    edge_kernel<<<2048, 256, 0, stream>>>(bf, eh, W1, b1, W2, b2, dst, sums, cnt, E);

    const int ntilesN = (N + 63) >> 6;
    node_kernel<<<ntilesN, 256, 0, stream>>>(sums, cnt, W3, b3, (float*)d_out, N);
}